// Round 9
// baseline (632.399 us; speedup 1.0000x reference)
//
#include <hip/hip_runtime.h>
#include <hip/hip_bf16.h>

// GAT forward: N=8192, IN=512, HID=256, OUT=64.
// w_ij = A_ij * max( e^{s1_i} e^{s2_j}, e^{0.2 s1_i} e^{0.2 s2_j} )
// Round 9: packA deleted. k_attn streams A directly (nontemporal, depth-2
// register prefetch) under the counted-vmcnt pipeline: per-iter VMEM order is
// pinned [uv][stage][A] so the barrier's vmcnt(2) drains stage exactly and
// never the A-prefetch. Swizzled LDS tile @4 blocks/CU kept (r8 best, 535.9).

typedef float f32x4 __attribute__((ext_vector_type(4)));
typedef short s16x8 __attribute__((ext_vector_type(8)));
typedef int   i32x4 __attribute__((ext_vector_type(4)));

#define NN 8192
#define INDIM 512
#define HIDD 256
#define OUTD 64

static __device__ __forceinline__ short f2bf(float x) {
    __hip_bfloat16 h = __float2bfloat16(x);
    return __builtin_bit_cast(short, h);
}

static __device__ __forceinline__ void split_bf(float x, short& hi, short& lo) {
    short h = f2bf(x);
    unsigned int hb = ((unsigned int)(unsigned short)h) << 16;
    float hf = __builtin_bit_cast(float, hb);
    hi = h;
    lo = f2bf(x - hf);
}

// ---------------- kernel 0: W1 (512x256 f32) -> W1^T hi/lo bf16 [256][512] -------------
__global__ void k_splitW1(const float* __restrict__ W1,
                          short* __restrict__ W1Thi, short* __restrict__ W1Tlo) {
    int t = blockIdx.x * 256 + threadIdx.x;   // t = n*512 + k
    int n = t >> 9;
    int k = t & 511;
    float x = W1[k * 256 + n];
    short hi, lo; split_bf(x, hi, lo);
    W1Thi[t] = hi;
    W1Tlo[t] = lo;
}

// ---------------- kernel 1: H1 = X@W1+b1 (split-bf16 MFMA, column-split) ---------------
// Grid 1024 = 512 row-tiles x 2 col-halves -> 4 blocks/CU (4 waves/SIMD TLP).
__global__ void __launch_bounds__(256, 4)
k_h1(const float* __restrict__ X, const short* __restrict__ W1Thi,
     const short* __restrict__ W1Tlo, const float* __restrict__ b1,
     const float* __restrict__ avec, unsigned short* __restrict__ H1TB,
     float* __restrict__ s1w, float* __restrict__ s2w) {
    __shared__ float s1p[4][16];
    __shared__ float s2p[4][16];
    const int tid = threadIdx.x;
    const int wn = tid >> 6, lane = tid & 63;
    const int q = lane >> 4, m16 = lane & 15;
    const int rt = blockIdx.x >> 1;
    const int ch = blockIdx.x & 1;
    const int i0 = rt * 16;
    const int irow = i0 + m16;
    const int colbase = ch * 128 + wn * 32;

    f32x4 zero4 = {0.f, 0.f, 0.f, 0.f};
    f32x4 acc[2];
#pragma unroll
    for (int nt = 0; nt < 2; ++nt) acc[nt] = zero4;

    const float* Xrow = X + (size_t)irow * INDIM;
    for (int kk = 0; kk < INDIM; kk += 32) {
        const int k0 = kk + q * 8;
        float4 xa = *(const float4*)(Xrow + k0);
        float4 xb = *(const float4*)(Xrow + k0 + 4);
        float xs[8] = {xa.x, xa.y, xa.z, xa.w, xb.x, xb.y, xb.z, xb.w};
        s16x8 ahi, alo;
#pragma unroll
        for (int j = 0; j < 8; ++j) { short h, l; split_bf(xs[j], h, l); ahi[j] = h; alo[j] = l; }
#pragma unroll
        for (int nt = 0; nt < 2; ++nt) {
            const int n = colbase + nt * 16 + m16;
            s16x8 bhi = *(const s16x8*)(W1Thi + n * INDIM + k0);
            s16x8 blo = *(const s16x8*)(W1Tlo + n * INDIM + k0);
            acc[nt] = __builtin_amdgcn_mfma_f32_16x16x32_bf16(ahi, bhi, acc[nt], 0, 0, 0);
            acc[nt] = __builtin_amdgcn_mfma_f32_16x16x32_bf16(ahi, blo, acc[nt], 0, 0, 0);
            acc[nt] = __builtin_amdgcn_mfma_f32_16x16x32_bf16(alo, bhi, acc[nt], 0, 0, 0);
        }
    }

    float p1[4] = {0.f, 0.f, 0.f, 0.f};
    float p2[4] = {0.f, 0.f, 0.f, 0.f};
    const int rowbase = i0 + q * 4;             // C rows: (lane>>4)*4 + r
    const int chunk = rowbase >> 5, win = rowbase & 31;
#pragma unroll
    for (int nt = 0; nt < 2; ++nt) {
        const int col = colbase + nt * 16 + m16;
        const float b1v = b1[col];
        const float a1v = avec[col];
        const float a2v = avec[HIDD + col];
        float v0 = acc[nt][0] + b1v;
        float v1 = acc[nt][1] + b1v;
        float v2 = acc[nt][2] + b1v;
        float v3 = acc[nt][3] + b1v;
        ushort4 us;
        us.x = (unsigned short)f2bf(v0);
        us.y = (unsigned short)f2bf(v1);
        us.z = (unsigned short)f2bf(v2);
        us.w = (unsigned short)f2bf(v3);
        *(ushort4*)(H1TB + (size_t)chunk * 8192 + col * 32 + win) = us;
        p1[0] += v0 * a1v; p1[1] += v1 * a1v; p1[2] += v2 * a1v; p1[3] += v3 * a1v;
        p2[0] += v0 * a2v; p2[1] += v1 * a2v; p2[2] += v2 * a2v; p2[3] += v3 * a2v;
    }
#pragma unroll
    for (int off = 1; off < 16; off <<= 1) {
#pragma unroll
        for (int r = 0; r < 4; ++r) {
            p1[r] += __shfl_xor(p1[r], off);
            p2[r] += __shfl_xor(p2[r], off);
        }
    }
    if (m16 == 0) {
#pragma unroll
        for (int r = 0; r < 4; ++r) {
            s1p[wn][q * 4 + r] = p1[r];
            s2p[wn][q * 4 + r] = p2[r];
        }
    }
    __syncthreads();
    if (tid < 16) {
        const int i = i0 + tid;
        float s1 = (s1p[0][tid] + s1p[1][tid]) + (s1p[2][tid] + s1p[3][tid]);
        float s2 = (s2p[0][tid] + s2p[1][tid]) + (s2p[2][tid] + s2p[3][tid]);
        atomicAdd(&s1w[i], s1);
        atomicAdd(&s2w[i], s2);
    }
}

// ---------------- kernel 1b: exp factors from s1/s2 totals -----------------------------
__global__ void __launch_bounds__(256)
k_uv(const float* __restrict__ s1w, const float* __restrict__ s2w,
     float* __restrict__ alw, float* __restrict__ bew, float* __restrict__ uvw) {
    const int i = blockIdx.x * 256 + threadIdx.x;
    const float s1 = s1w[i], s2 = s2w[i];
    alw[i] = expf(s1);
    bew[i] = expf(0.2f * s1);
    uvw[2 * i]     = expf(s2);
    uvw[2 * i + 1] = expf(0.2f * s2);
}

// ---------------- kernel 2: H2acc += W @ H1 (LDS dbuf + inline-A + XOR-swizzle) --------
// Grid 1024 = mb(256, 32 rows) x ks(4, 2048 cols). Block 256 = 4 waves; 4 blk/CU.
// VMEM queue discipline (in-order retirement):
//   per iter kk issue order: [uv(kk+1) x4] SB [stage(kk+1) x4] SB [A(kk+2) x2] SB
//   wv-gen(kk) waits uv(kk)  -> compiler emits vmcnt(6): stage(kk)+A(kk+1) stay.
//   barrier cluster waits vmcnt(2): drains stage(kk) exactly, A(kk+1) stays.
//   A(kk) consumed 2 iters after issue -> ~900cy HBM latency covered.
// Tail made uniform by clamped A address (min(kk+2,63)): 2 A-ops every iter.
// LDS tile swizzle as r7/r8 (bank conflicts 0, verified).
__global__ void __launch_bounds__(256, 4)
k_attn(const int* __restrict__ A, const unsigned short* __restrict__ H1TB,
       const float* __restrict__ alw, const float* __restrict__ bew,
       const float* __restrict__ uvw,
       float* __restrict__ H2acc, float* __restrict__ Zw) {
    __shared__ unsigned short tile[2][8192];   // 32 KB: 2 x [256 hid][32 j], swizzled

    const int tid = threadIdx.x;
    const int wave = tid >> 6, lane = tid & 63;
    const int q = lane >> 4, m16 = lane & 15;
    const int wm = wave & 1, wn = wave >> 1;
    const int mb = blockIdx.x & 255;
    const int ks = blockIdx.x >> 8;
    const int i = mb * 32 + wm * 16 + m16;
    const float al = alw[i], be = bew[i];

    // staging source: pre-swizzled global offset (inverse of read-side XOR)
    const int tswz = tid ^ ((tid >> 3) & 3);
    const unsigned short* gp = H1TB + (size_t)ks * 64 * 8192 + tswz * 8;
    __attribute__((address_space(3))) unsigned short* tl =
        (__attribute__((address_space(3))) unsigned short*)&tile[0][0];

    // A row pointer: per (row i, kk) the 4 q-groups cover 128 contiguous bytes.
    const int* Arow = A + (size_t)i * NN + ks * 2048 + q * 8;
    const float* uvp = uvw + 2 * (ks * 2048 + q * 8);

    // read-side: h = wn*128 + nt*16 + m16; xor term is nt-independent
    const int hb0 = wn * 128 + m16;
    const int qx = (q * 8) ^ (((hb0 >> 1) & 3) << 3);   // swizzled j-offset

    f32x4 zero4 = {0.f, 0.f, 0.f, 0.f};
    f32x4 acc[8];
#pragma unroll
    for (int nt = 0; nt < 8; ++nt) acc[nt] = zero4;
    float zacc = 0.f;

    // ---- prologue: queue order = uv(0) | A(0) | stage(0) | A(1) ----
    float4 uv0 = *(const float4*)(uvp);
    float4 uv1 = *(const float4*)(uvp + 4);
    float4 uv2 = *(const float4*)(uvp + 8);
    float4 uv3 = *(const float4*)(uvp + 12);
    uvp += 64;
    __builtin_amdgcn_sched_barrier(0);
    i32x4 Aq0[2], Aq1[2];
    Aq0[0] = __builtin_nontemporal_load((const i32x4*)(Arow));
    Aq1[0] = __builtin_nontemporal_load((const i32x4*)(Arow + 4));
    __builtin_amdgcn_sched_barrier(0);
#pragma unroll
    for (int c = 0; c < 4; ++c)
        __builtin_amdgcn_global_load_lds(
            (const __attribute__((address_space(1))) void*)(gp + c * 2048),
            (__attribute__((address_space(3))) void*)(tl + c * 2048 + tid * 8),
            16, 0, 0);
    gp += 8192;
    __builtin_amdgcn_sched_barrier(0);
    Aq0[1] = __builtin_nontemporal_load((const i32x4*)(Arow + 32));
    Aq1[1] = __builtin_nontemporal_load((const i32x4*)(Arow + 36));
    __builtin_amdgcn_sched_barrier(0);

    for (int kk4 = 0; kk4 < 16; ++kk4) {
#pragma unroll
        for (int kkq = 0; kkq < 4; ++kkq) {
            const int kk = kk4 * 4 + kkq;
            const i32x4 av0 = Aq0[kkq & 1];       // A(kk), issued 2 iters ago
            const i32x4 av1 = Aq1[kkq & 1];

            // ---- weight generation for this K-step ----
            float wv[8];
            wv[0] = (av0[0] > 0) ? fmaxf(al * uv0.x, be * uv0.y) : 0.f;
            wv[1] = (av0[1] > 0) ? fmaxf(al * uv0.z, be * uv0.w) : 0.f;
            wv[2] = (av0[2] > 0) ? fmaxf(al * uv1.x, be * uv1.y) : 0.f;
            wv[3] = (av0[3] > 0) ? fmaxf(al * uv1.z, be * uv1.w) : 0.f;
            wv[4] = (av1[0] > 0) ? fmaxf(al * uv2.x, be * uv2.y) : 0.f;
            wv[5] = (av1[1] > 0) ? fmaxf(al * uv2.z, be * uv2.w) : 0.f;
            wv[6] = (av1[2] > 0) ? fmaxf(al * uv3.x, be * uv3.y) : 0.f;
            wv[7] = (av1[3] > 0) ? fmaxf(al * uv3.z, be * uv3.w) : 0.f;
            zacc += (wv[0] + wv[1] + wv[2] + wv[3]) + (wv[4] + wv[5] + wv[6] + wv[7]);
            s16x8 af;
#pragma unroll
            for (int j = 0; j < 8; ++j) af[j] = f2bf(wv[j]);

            // ---- barrier cluster: drain stage(kk) only; A(kk+1) stays in flight ----
            __builtin_amdgcn_sched_barrier(0);
            asm volatile("s_waitcnt vmcnt(2)" ::: "memory");
            __builtin_amdgcn_s_barrier();
            __builtin_amdgcn_sched_barrier(0);

            if (kk < 63) {
                // uv(kk+1) first (oldest in queue) ...
                uv0 = *(const float4*)(uvp);
                uv1 = *(const float4*)(uvp + 4);
                uv2 = *(const float4*)(uvp + 8);
                uv3 = *(const float4*)(uvp + 12);
                uvp += 64;
                __builtin_amdgcn_sched_barrier(0);
                // ... then stage(kk+1) into the other buffer
                const int nb = ((kk + 1) & 1) * 8192;
#pragma unroll
                for (int c = 0; c < 4; ++c)
                    __builtin_amdgcn_global_load_lds(
                        (const __attribute__((address_space(1))) void*)(gp + c * 2048),
                        (__attribute__((address_space(3))) void*)(tl + nb + c * 2048 + tid * 8),
                        16, 0, 0);
                gp += 8192;
                __builtin_amdgcn_sched_barrier(0);
            }
            // A(kk+2) last (newest); clamped tail keeps 2 A-ops/iter -> vmcnt(2) uniform
            {
                const int ka = (kk + 2 <= 63) ? (kk + 2) : 63;
                const int* ap = Arow + ka * 32;
                Aq0[kkq & 1] = __builtin_nontemporal_load((const i32x4*)(ap));
                Aq1[kkq & 1] = __builtin_nontemporal_load((const i32x4*)(ap + 4));
            }
            __builtin_amdgcn_sched_barrier(0);

            // ---- MFMA phase on buf[kk&1] (swizzled reads) ----
            const unsigned short* tb = &tile[kk & 1][0];
#pragma unroll
            for (int nt = 0; nt < 8; ++nt) {
                s16x8 bfv = *(const s16x8*)(tb + (hb0 + nt * 16) * 32 + qx);
                acc[nt] = __builtin_amdgcn_mfma_f32_16x16x32_bf16(af, bfv, acc[nt], 0, 0, 0);
            }
        }
    }

    // Z row-sum: reduce across q groups; one atomic per row (wn==0 waves only).
    zacc += __shfl_xor(zacc, 16);
    zacc += __shfl_xor(zacc, 32);
    if (wn == 0 && q == 0) atomicAdd(&Zw[i], zacc);

    const int rowbase = mb * 32 + wm * 16 + q * 4;
#pragma unroll
    for (int nt = 0; nt < 8; ++nt) {
        const int col = wn * 128 + nt * 16 + m16;
#pragma unroll
        for (int r = 0; r < 4; ++r)
            atomicAdd(&H2acc[(size_t)(rowbase + r) * HIDD + col], acc[nt][r]);
    }
}

// ---------------- kernel 3: out = sigmoid((H2acc/Z) @ Omega + beta) --------------------
// Grid 512 (16 rows/block, 2 blocks/CU by 64KB LDS) for 2x TLP on the H2acc read.
__global__ void __launch_bounds__(256)
k_out(const float* __restrict__ H2acc, const float* __restrict__ Zw,
      const float* __restrict__ Omega, const float* __restrict__ beta,
      float* __restrict__ out) {
    __shared__ float om[HIDD * OUTD];  // 64 KB
    const int tid = threadIdx.x;
    for (int idx = tid; idx < HIDD * OUTD; idx += 256) om[idx] = Omega[idx];
    __syncthreads();
    const int wave = tid >> 6, o = tid & 63;
    const float bv = beta[o];
    for (int rr = 0; rr < 4; ++rr) {
        const int i = blockIdx.x * 16 + wave * 4 + rr;
        const float4* H2v = (const float4*)(H2acc + (size_t)i * HIDD);
        float acc = 0.f;
#pragma unroll 4
        for (int c4 = 0; c4 < 64; ++c4) {
            float4 h = H2v[c4];
            const int cb = c4 * 4;
            acc = fmaf(h.x, om[(cb + 0) * OUTD + o], acc);
            acc = fmaf(h.y, om[(cb + 1) * OUTD + o], acc);
            acc = fmaf(h.z, om[(cb + 2) * OUTD + o], acc);
            acc = fmaf(h.w, om[(cb + 3) * OUTD + o], acc);
        }
        const float zinv = 1.0f / Zw[i];
        const float logit = acc * zinv + bv;
        out[(size_t)i * OUTD + o] = 1.0f / (1.0f + expf(-logit));
    }
}

extern "C" void kernel_launch(void* const* d_in, const int* in_sizes, int n_in,
                              void* d_out, int out_size, void* d_ws, size_t ws_size,
                              hipStream_t stream) {
    const float* X     = (const float*)d_in[0];
    const int*   A     = (const int*)d_in[1];
    const float* W1    = (const float*)d_in[2];
    const float* b1    = (const float*)d_in[3];
    const float* avec  = (const float*)d_in[4];
    const float* Omega = (const float*)d_in[5];
    const float* beta  = (const float*)d_in[6];
    float* out = (float*)d_out;

    char* ws = (char*)d_ws;
    unsigned short* H1TB = (unsigned short*)(ws + 0);       // 4,194,304
    short* W1Thi = (short*)(ws + 4194304);                  // 262,144
    short* W1Tlo = (short*)(ws + 4456448);                  // 262,144
    float* s1w   = (float*)(ws + 4718592);                  // 32,768
    float* s2w   = (float*)(ws + 4751360);                  // 32,768
    float* alw   = (float*)(ws + 4784128);                  // 32,768
    float* bew   = (float*)(ws + 4816896);                  // 32,768
    float* uvw   = (float*)(ws + 4849664);                  // 65,536
    float* Zw    = (float*)(ws + 4915200);                  // 32,768
    float* H2acc = (float*)(ws + 4947968);                  // 8,388,608 (end 13,336,576)

    // zero s1w..H2acc (8,617,984 B): covers s1w/s2w atomics, Zw, H2acc.
    hipMemsetAsync(s1w, 0, 8617984, stream);

    k_splitW1<<<512, 256, 0, stream>>>(W1, W1Thi, W1Tlo);
    k_h1<<<1024, 256, 0, stream>>>(X, W1Thi, W1Tlo, b1, avec, H1TB, s1w, s2w);
    k_uv<<<32, 256, 0, stream>>>(s1w, s2w, alw, bew, uvw);
    k_attn<<<1024, 256, 0, stream>>>(A, H1TB, alw, bew, uvw, H2acc, Zw);
    k_out<<<512, 256, 0, stream>>>(H2acc, Zw, Omega, beta, out);
}

// Round 10
// 580.443 us; speedup vs baseline: 1.0895x; 1.0895x over previous
//
#include <hip/hip_runtime.h>
#include <hip/hip_bf16.h>

// GAT forward: N=8192, IN=512, HID=256, OUT=64.
// w_ij = A_ij * max( e^{s1_i} e^{s2_j}, e^{0.2 s1_i} e^{0.2 s2_j} )
// Round 10: r8 k_attn loop (proven best) with ATOMIC-FREE epilogue: per-ks
// output slabs H2s/Zs written with plain once-per-line stores (no RMW, no
// pre-zero). k_out sums the 4 slabs. packA restored (r9 inline-A refuted:
// nontemporal didn't bypass L2; 256MB stream thrashed dirty atomic lines).

typedef float f32x4 __attribute__((ext_vector_type(4)));
typedef short s16x8 __attribute__((ext_vector_type(8)));

#define NN 8192
#define INDIM 512
#define HIDD 256
#define OUTD 64

static __device__ __forceinline__ short f2bf(float x) {
    __hip_bfloat16 h = __float2bfloat16(x);
    return __builtin_bit_cast(short, h);
}

static __device__ __forceinline__ void split_bf(float x, short& hi, short& lo) {
    short h = f2bf(x);
    unsigned int hb = ((unsigned int)(unsigned short)h) << 16;
    float hf = __builtin_bit_cast(float, hb);
    hi = h;
    lo = f2bf(x - hf);
}

// ---------------- kernel A: pack A (8192x8192 int32) -> bitmask ------------------------
// dword idx i*256 + ks*64 + q*16 + kk4, byte kkq, bit j <-> col = ks*2048+(kk4*4+kkq)*32+q*8+j
__global__ void __launch_bounds__(256)
k_packA(const int* __restrict__ A, unsigned int* __restrict__ Apk) {
    const int i = blockIdx.x;
    const int t = threadIdx.x;               // t = ks*64 + q*16 + kk0
    const int ks = t >> 6, q = (t >> 4) & 3, kk0 = t & 15;
    const int* Ar = A + (size_t)i * NN;
    unsigned int out = 0;
#pragma unroll
    for (int kkq = 0; kkq < 4; ++kkq) {
        const int kk = kk0 * 4 + kkq;
        const int c0 = ks * 2048 + kk * 32 + q * 8;
        int4 v0 = *(const int4*)(Ar + c0);
        int4 v1 = *(const int4*)(Ar + c0 + 4);
        unsigned int b = 0;
        b |= (v0.x > 0) ? 1u : 0u;
        b |= (v0.y > 0) ? 2u : 0u;
        b |= (v0.z > 0) ? 4u : 0u;
        b |= (v0.w > 0) ? 8u : 0u;
        b |= (v1.x > 0) ? 16u : 0u;
        b |= (v1.y > 0) ? 32u : 0u;
        b |= (v1.z > 0) ? 64u : 0u;
        b |= (v1.w > 0) ? 128u : 0u;
        out |= b << (kkq * 8);
    }
    Apk[(size_t)i * 256 + t] = out;
}

// ---------------- kernel 0: W1 (512x256 f32) -> W1^T hi/lo bf16 [256][512] -------------
__global__ void k_splitW1(const float* __restrict__ W1,
                          short* __restrict__ W1Thi, short* __restrict__ W1Tlo) {
    int t = blockIdx.x * 256 + threadIdx.x;   // t = n*512 + k
    int n = t >> 9;
    int k = t & 511;
    float x = W1[k * 256 + n];
    short hi, lo; split_bf(x, hi, lo);
    W1Thi[t] = hi;
    W1Tlo[t] = lo;
}

// ---------------- kernel 1: H1 = X@W1+b1 (split-bf16 MFMA, column-split) ---------------
// Grid 1024 = 512 row-tiles x 2 col-halves -> 4 blocks/CU (4 waves/SIMD TLP).
__global__ void __launch_bounds__(256, 4)
k_h1(const float* __restrict__ X, const short* __restrict__ W1Thi,
     const short* __restrict__ W1Tlo, const float* __restrict__ b1,
     const float* __restrict__ avec, unsigned short* __restrict__ H1TB,
     float* __restrict__ s1w, float* __restrict__ s2w) {
    __shared__ float s1p[4][16];
    __shared__ float s2p[4][16];
    const int tid = threadIdx.x;
    const int wn = tid >> 6, lane = tid & 63;
    const int q = lane >> 4, m16 = lane & 15;
    const int rt = blockIdx.x >> 1;
    const int ch = blockIdx.x & 1;
    const int i0 = rt * 16;
    const int irow = i0 + m16;
    const int colbase = ch * 128 + wn * 32;

    f32x4 zero4 = {0.f, 0.f, 0.f, 0.f};
    f32x4 acc[2];
#pragma unroll
    for (int nt = 0; nt < 2; ++nt) acc[nt] = zero4;

    const float* Xrow = X + (size_t)irow * INDIM;
    for (int kk = 0; kk < INDIM; kk += 32) {
        const int k0 = kk + q * 8;
        float4 xa = *(const float4*)(Xrow + k0);
        float4 xb = *(const float4*)(Xrow + k0 + 4);
        float xs[8] = {xa.x, xa.y, xa.z, xa.w, xb.x, xb.y, xb.z, xb.w};
        s16x8 ahi, alo;
#pragma unroll
        for (int j = 0; j < 8; ++j) { short h, l; split_bf(xs[j], h, l); ahi[j] = h; alo[j] = l; }
#pragma unroll
        for (int nt = 0; nt < 2; ++nt) {
            const int n = colbase + nt * 16 + m16;
            s16x8 bhi = *(const s16x8*)(W1Thi + n * INDIM + k0);
            s16x8 blo = *(const s16x8*)(W1Tlo + n * INDIM + k0);
            acc[nt] = __builtin_amdgcn_mfma_f32_16x16x32_bf16(ahi, bhi, acc[nt], 0, 0, 0);
            acc[nt] = __builtin_amdgcn_mfma_f32_16x16x32_bf16(ahi, blo, acc[nt], 0, 0, 0);
            acc[nt] = __builtin_amdgcn_mfma_f32_16x16x32_bf16(alo, bhi, acc[nt], 0, 0, 0);
        }
    }

    float p1[4] = {0.f, 0.f, 0.f, 0.f};
    float p2[4] = {0.f, 0.f, 0.f, 0.f};
    const int rowbase = i0 + q * 4;             // C rows: (lane>>4)*4 + r
    const int chunk = rowbase >> 5, win = rowbase & 31;
#pragma unroll
    for (int nt = 0; nt < 2; ++nt) {
        const int col = colbase + nt * 16 + m16;
        const float b1v = b1[col];
        const float a1v = avec[col];
        const float a2v = avec[HIDD + col];
        float v0 = acc[nt][0] + b1v;
        float v1 = acc[nt][1] + b1v;
        float v2 = acc[nt][2] + b1v;
        float v3 = acc[nt][3] + b1v;
        ushort4 us;
        us.x = (unsigned short)f2bf(v0);
        us.y = (unsigned short)f2bf(v1);
        us.z = (unsigned short)f2bf(v2);
        us.w = (unsigned short)f2bf(v3);
        *(ushort4*)(H1TB + (size_t)chunk * 8192 + col * 32 + win) = us;
        p1[0] += v0 * a1v; p1[1] += v1 * a1v; p1[2] += v2 * a1v; p1[3] += v3 * a1v;
        p2[0] += v0 * a2v; p2[1] += v1 * a2v; p2[2] += v2 * a2v; p2[3] += v3 * a2v;
    }
#pragma unroll
    for (int off = 1; off < 16; off <<= 1) {
#pragma unroll
        for (int r = 0; r < 4; ++r) {
            p1[r] += __shfl_xor(p1[r], off);
            p2[r] += __shfl_xor(p2[r], off);
        }
    }
    if (m16 == 0) {
#pragma unroll
        for (int r = 0; r < 4; ++r) {
            s1p[wn][q * 4 + r] = p1[r];
            s2p[wn][q * 4 + r] = p2[r];
        }
    }
    __syncthreads();
    if (tid < 16) {
        const int i = i0 + tid;
        float s1 = (s1p[0][tid] + s1p[1][tid]) + (s1p[2][tid] + s1p[3][tid]);
        float s2 = (s2p[0][tid] + s2p[1][tid]) + (s2p[2][tid] + s2p[3][tid]);
        atomicAdd(&s1w[i], s1);
        atomicAdd(&s2w[i], s2);
    }
}

// ---------------- kernel 1b: exp factors from s1/s2 totals -----------------------------
__global__ void __launch_bounds__(256)
k_uv(const float* __restrict__ s1w, const float* __restrict__ s2w,
     float* __restrict__ alw, float* __restrict__ bew, float* __restrict__ uvw) {
    const int i = blockIdx.x * 256 + threadIdx.x;
    const float s1 = s1w[i], s2 = s2w[i];
    alw[i] = expf(s1);
    bew[i] = expf(0.2f * s1);
    uvw[2 * i]     = expf(s2);
    uvw[2 * i + 1] = expf(0.2f * s2);
}

// ---------------- kernel 2: H2s[ks] = W @ H1 (LDS dbuf + bitmask + XOR-swizzle) --------
// Grid 1024 = mb(256, 32 rows) x ks(4, 2048 cols). Block 256 = 4 waves; 4 blk/CU.
// K-loop identical to r8 (counted vmcnt, swizzled tile, conflicts=0 verified).
// Epilogue: plain once-per-line stores into per-ks slabs -> zero atomics,
// zero pre-init. Each (ks,row,col) owned by exactly one thread.
__global__ void __launch_bounds__(256, 4)
k_attn(const unsigned int* __restrict__ Apk, const unsigned short* __restrict__ H1TB,
       const float* __restrict__ alw, const float* __restrict__ bew,
       const float* __restrict__ uvw,
       float* __restrict__ H2s, float* __restrict__ Zs) {
    __shared__ unsigned short tile[2][8192];   // 32 KB: 2 x [256 hid][32 j], swizzled

    const int tid = threadIdx.x;
    const int wave = tid >> 6, lane = tid & 63;
    const int q = lane >> 4, m16 = lane & 15;
    const int wm = wave & 1, wn = wave >> 1;
    const int mb = blockIdx.x & 255;
    const int ks = blockIdx.x >> 8;
    const int i = mb * 32 + wm * 16 + m16;
    const float al = alw[i], be = bew[i];

    // staging source: pre-swizzled global offset (inverse of read-side XOR)
    const int tswz = tid ^ ((tid >> 3) & 3);
    const unsigned short* gp = H1TB + (size_t)ks * 64 * 8192 + tswz * 8;
    __attribute__((address_space(3))) unsigned short* tl =
        (__attribute__((address_space(3))) unsigned short*)&tile[0][0];

    const unsigned int* Ab = Apk + (size_t)i * 256 + ks * 64 + q * 16;
    const float* uvp = uvw + 2 * (ks * 2048 + q * 8);

    // read-side: h = wn*128 + nt*16 + m16; xor term is nt-independent
    const int hb0 = wn * 128 + m16;
    const int qx = (q * 8) ^ (((hb0 >> 1) & 3) << 3);   // swizzled j-offset

    f32x4 zero4 = {0.f, 0.f, 0.f, 0.f};
    f32x4 acc[8];
#pragma unroll
    for (int nt = 0; nt < 8; ++nt) acc[nt] = zero4;
    float zacc = 0.f;

    // ---- prologue: stage tile 0 into buf 0, then uv(0), then A dword 0 ----
#pragma unroll
    for (int c = 0; c < 4; ++c)
        __builtin_amdgcn_global_load_lds(
            (const __attribute__((address_space(1))) void*)(gp + c * 2048),
            (__attribute__((address_space(3))) void*)(tl + c * 2048 + tid * 8),
            16, 0, 0);
    gp += 8192;

    float4 uv0 = *(const float4*)(uvp);
    float4 uv1 = *(const float4*)(uvp + 4);
    float4 uv2 = *(const float4*)(uvp + 8);
    float4 uv3 = *(const float4*)(uvp + 12);
    uvp += 64;
    unsigned int a4 = Ab[0];

    for (int kk4 = 0; kk4 < 16; ++kk4) {
        // prefetch next A dword (covers ~1 K-step of latency before in-order retire)
        unsigned int a4n = Ab[(kk4 + 1) & 15];
#pragma unroll
        for (int kkq = 0; kkq < 4; ++kkq) {
            const int kk = kk4 * 4 + kkq;
            const unsigned int ab = a4 >> (kkq * 8);

            // ---- weight generation for this K-step ----
            float wv[8];
            wv[0] = (ab & 1u)   ? fmaxf(al * uv0.x, be * uv0.y) : 0.f;
            wv[1] = (ab & 2u)   ? fmaxf(al * uv0.z, be * uv0.w) : 0.f;
            wv[2] = (ab & 4u)   ? fmaxf(al * uv1.x, be * uv1.y) : 0.f;
            wv[3] = (ab & 8u)   ? fmaxf(al * uv1.z, be * uv1.w) : 0.f;
            wv[4] = (ab & 16u)  ? fmaxf(al * uv2.x, be * uv2.y) : 0.f;
            wv[5] = (ab & 32u)  ? fmaxf(al * uv2.z, be * uv2.w) : 0.f;
            wv[6] = (ab & 64u)  ? fmaxf(al * uv3.x, be * uv3.y) : 0.f;
            wv[7] = (ab & 128u) ? fmaxf(al * uv3.z, be * uv3.w) : 0.f;
            zacc += (wv[0] + wv[1] + wv[2] + wv[3]) + (wv[4] + wv[5] + wv[6] + wv[7]);
            s16x8 af;
#pragma unroll
            for (int j = 0; j < 8; ++j) af[j] = f2bf(wv[j]);

            // ---- barrier cluster: drain stage(kk) (issued one K-step ago) ----
            // At kkq==0 the a4n prefetch (issued above) is in flight: keep it.
            __builtin_amdgcn_sched_barrier(0);
            if (kkq == 0) asm volatile("s_waitcnt vmcnt(1)" ::: "memory");
            else          asm volatile("s_waitcnt vmcnt(0)" ::: "memory");
            __builtin_amdgcn_s_barrier();
            __builtin_amdgcn_sched_barrier(0);

            if (kk < 63) {
                // uv prefetch first, then issue stage(kk+1) into the other buffer
                uv0 = *(const float4*)(uvp);
                uv1 = *(const float4*)(uvp + 4);
                uv2 = *(const float4*)(uvp + 8);
                uv3 = *(const float4*)(uvp + 12);
                uvp += 64;
                const int nb = ((kk + 1) & 1) * 8192;
#pragma unroll
                for (int c = 0; c < 4; ++c)
                    __builtin_amdgcn_global_load_lds(
                        (const __attribute__((address_space(1))) void*)(gp + c * 2048),
                        (__attribute__((address_space(3))) void*)(tl + nb + c * 2048 + tid * 8),
                        16, 0, 0);
                gp += 8192;
            }

            // ---- MFMA phase on buf[kk&1] (swizzled reads) ----
            const unsigned short* tb = &tile[kk & 1][0];
#pragma unroll
            for (int nt = 0; nt < 8; ++nt) {
                s16x8 bfv = *(const s16x8*)(tb + (hb0 + nt * 16) * 32 + qx);
                acc[nt] = __builtin_amdgcn_mfma_f32_16x16x32_bf16(af, bfv, acc[nt], 0, 0, 0);
            }
        }
        a4 = a4n;
    }

    // Z row-sum: reduce across q groups; wn==0 waves (wm 0/1) cover all 32 rows.
    zacc += __shfl_xor(zacc, 16);
    zacc += __shfl_xor(zacc, 32);
    if (wn == 0 && q == 0) Zs[(size_t)ks * NN + i] = zacc;

    // Plain stores into slab ks: local row = wm*16 + q*4 + r, col = wn*128+nt*16+m16.
    float* Hb = H2s + ((size_t)ks * NN + (size_t)mb * 32 + wm * 16) * HIDD;
#pragma unroll
    for (int nt = 0; nt < 8; ++nt) {
        const int col = wn * 128 + nt * 16 + m16;
#pragma unroll
        for (int r = 0; r < 4; ++r)
            Hb[(size_t)(q * 4 + r) * HIDD + col] = acc[nt][r];
    }
}

// ---------------- kernel 3: out = sigmoid((sum_ks H2s / sum_ks Zs) @ Omega + beta) -----
// Grid 512 (16 rows/block, 2 blocks/CU by 64KB LDS).
__global__ void __launch_bounds__(256)
k_out(const float* __restrict__ H2s, const float* __restrict__ Zs,
      const float* __restrict__ Omega, const float* __restrict__ beta,
      float* __restrict__ out) {
    __shared__ float om[HIDD * OUTD];  // 64 KB
    const int tid = threadIdx.x;
    for (int idx = tid; idx < HIDD * OUTD; idx += 256) om[idx] = Omega[idx];
    __syncthreads();
    const int wave = tid >> 6, o = tid & 63;
    const float bv = beta[o];
    for (int rr = 0; rr < 4; ++rr) {
        const int i = blockIdx.x * 16 + wave * 4 + rr;
        const float4* h0 = (const float4*)(H2s + (size_t)i * HIDD);
        const float4* h1 = (const float4*)(H2s + (size_t)(NN + i) * HIDD);
        const float4* h2 = (const float4*)(H2s + (size_t)(2 * NN + i) * HIDD);
        const float4* h3 = (const float4*)(H2s + (size_t)(3 * NN + i) * HIDD);
        float acc = 0.f;
#pragma unroll 4
        for (int c4 = 0; c4 < 64; ++c4) {
            float4 a = h0[c4], b = h1[c4], c = h2[c4], d = h3[c4];
            const float sx = (a.x + b.x) + (c.x + d.x);
            const float sy = (a.y + b.y) + (c.y + d.y);
            const float sz = (a.z + b.z) + (c.z + d.z);
            const float sw = (a.w + b.w) + (c.w + d.w);
            const int cb = c4 * 4;
            acc = fmaf(sx, om[(cb + 0) * OUTD + o], acc);
            acc = fmaf(sy, om[(cb + 1) * OUTD + o], acc);
            acc = fmaf(sz, om[(cb + 2) * OUTD + o], acc);
            acc = fmaf(sw, om[(cb + 3) * OUTD + o], acc);
        }
        const float z = (Zs[i] + Zs[NN + i]) + (Zs[2 * NN + i] + Zs[3 * NN + i]);
        const float logit = acc / z + bv;
        out[(size_t)i * OUTD + o] = 1.0f / (1.0f + expf(-logit));
    }
}

extern "C" void kernel_launch(void* const* d_in, const int* in_sizes, int n_in,
                              void* d_out, int out_size, void* d_ws, size_t ws_size,
                              hipStream_t stream) {
    const float* X     = (const float*)d_in[0];
    const int*   A     = (const int*)d_in[1];
    const float* W1    = (const float*)d_in[2];
    const float* b1    = (const float*)d_in[3];
    const float* avec  = (const float*)d_in[4];
    const float* Omega = (const float*)d_in[5];
    const float* beta  = (const float*)d_in[6];
    float* out = (float*)d_out;

    char* ws = (char*)d_ws;
    unsigned short* H1TB = (unsigned short*)(ws + 0);       // 4,194,304
    short* W1Thi = (short*)(ws + 4194304);                  // 262,144
    short* W1Tlo = (short*)(ws + 4456448);                  // 262,144
    float* s1w   = (float*)(ws + 4718592);                  // 32,768
    float* s2w   = (float*)(ws + 4751360);                  // 32,768
    float* alw   = (float*)(ws + 4784128);                  // 32,768
    float* bew   = (float*)(ws + 4816896);                  // 32,768
    float* uvw   = (float*)(ws + 4849664);                  // 65,536
    unsigned int* Apk = (unsigned int*)(ws + 4915200);      // 8,388,608
    float* H2s   = (float*)(ws + 13303808);                 // 33,554,432 (4 slabs)
    float* Zs    = (float*)(ws + 46858240);                 // 131,072 (end 46,989,312)

    // zero only s1w/s2w (64 KB) for k_h1's cross-block atomic partials.
    hipMemsetAsync(s1w, 0, 65536, stream);

    k_splitW1<<<512, 256, 0, stream>>>(W1, W1Thi, W1Tlo);
    k_h1<<<1024, 256, 0, stream>>>(X, W1Thi, W1Tlo, b1, avec, H1TB, s1w, s2w);
    k_uv<<<32, 256, 0, stream>>>(s1w, s2w, alw, bew, uvw);
    k_packA<<<8192, 256, 0, stream>>>(A, Apk);
    k_attn<<<1024, 256, 0, stream>>>(Apk, H1TB, alw, bew, uvw, H2s, Zs);
    k_out<<<512, 256, 0, stream>>>(H2s, Zs, Omega, beta, out);
}

// Round 11
// 536.342 us; speedup vs baseline: 1.1791x; 1.0822x over previous
//
#include <hip/hip_runtime.h>
#include <hip/hip_bf16.h>

// GAT forward: N=8192, IN=512, HID=256, OUT=64.
// w_ij = A_ij * max( e^{s1_i} e^{s2_j}, e^{0.2 s1_i} e^{0.2 s2_j} )
// Round 11: r8 (best, 535.9) + XCD-pinned ks in k_attn: ks = (bid&7)>>1 so each
// XCD's resident blocks share ONE 1MB H1TB slice -> slice stays L2-resident,
// staging L2-miss traffic (147MB observed) collapses. r10 slab design reverted
// (regressed 45us: atomics were cheap; slabs added 60MB of fabric traffic).

typedef float f32x4 __attribute__((ext_vector_type(4)));
typedef short s16x8 __attribute__((ext_vector_type(8)));

#define NN 8192
#define INDIM 512
#define HIDD 256
#define OUTD 64

static __device__ __forceinline__ short f2bf(float x) {
    __hip_bfloat16 h = __float2bfloat16(x);
    return __builtin_bit_cast(short, h);
}

static __device__ __forceinline__ void split_bf(float x, short& hi, short& lo) {
    short h = f2bf(x);
    unsigned int hb = ((unsigned int)(unsigned short)h) << 16;
    float hf = __builtin_bit_cast(float, hb);
    hi = h;
    lo = f2bf(x - hf);
}

// ---------------- kernel A: pack A (8192x8192 int32) -> bitmask ------------------------
// dword idx i*256 + ks*64 + q*16 + kk4, byte kkq, bit j <-> col = ks*2048+(kk4*4+kkq)*32+q*8+j
__global__ void __launch_bounds__(256)
k_packA(const int* __restrict__ A, unsigned int* __restrict__ Apk) {
    const int i = blockIdx.x;
    const int t = threadIdx.x;               // t = ks*64 + q*16 + kk0
    const int ks = t >> 6, q = (t >> 4) & 3, kk0 = t & 15;
    const int* Ar = A + (size_t)i * NN;
    unsigned int out = 0;
#pragma unroll
    for (int kkq = 0; kkq < 4; ++kkq) {
        const int kk = kk0 * 4 + kkq;
        const int c0 = ks * 2048 + kk * 32 + q * 8;
        int4 v0 = *(const int4*)(Ar + c0);
        int4 v1 = *(const int4*)(Ar + c0 + 4);
        unsigned int b = 0;
        b |= (v0.x > 0) ? 1u : 0u;
        b |= (v0.y > 0) ? 2u : 0u;
        b |= (v0.z > 0) ? 4u : 0u;
        b |= (v0.w > 0) ? 8u : 0u;
        b |= (v1.x > 0) ? 16u : 0u;
        b |= (v1.y > 0) ? 32u : 0u;
        b |= (v1.z > 0) ? 64u : 0u;
        b |= (v1.w > 0) ? 128u : 0u;
        out |= b << (kkq * 8);
    }
    Apk[(size_t)i * 256 + t] = out;
}

// ---------------- kernel 0: W1 (512x256 f32) -> W1^T hi/lo bf16 [256][512] -------------
__global__ void k_splitW1(const float* __restrict__ W1,
                          short* __restrict__ W1Thi, short* __restrict__ W1Tlo) {
    int t = blockIdx.x * 256 + threadIdx.x;   // t = n*512 + k
    int n = t >> 9;
    int k = t & 511;
    float x = W1[k * 256 + n];
    short hi, lo; split_bf(x, hi, lo);
    W1Thi[t] = hi;
    W1Tlo[t] = lo;
}

// ---------------- kernel 1: H1 = X@W1+b1 (split-bf16 MFMA, column-split) ---------------
// Grid 1024 = 512 row-tiles x 2 col-halves -> 4 blocks/CU (4 waves/SIMD TLP).
__global__ void __launch_bounds__(256, 4)
k_h1(const float* __restrict__ X, const short* __restrict__ W1Thi,
     const short* __restrict__ W1Tlo, const float* __restrict__ b1,
     const float* __restrict__ avec, unsigned short* __restrict__ H1TB,
     float* __restrict__ s1w, float* __restrict__ s2w) {
    __shared__ float s1p[4][16];
    __shared__ float s2p[4][16];
    const int tid = threadIdx.x;
    const int wn = tid >> 6, lane = tid & 63;
    const int q = lane >> 4, m16 = lane & 15;
    const int rt = blockIdx.x >> 1;
    const int ch = blockIdx.x & 1;
    const int i0 = rt * 16;
    const int irow = i0 + m16;
    const int colbase = ch * 128 + wn * 32;

    f32x4 zero4 = {0.f, 0.f, 0.f, 0.f};
    f32x4 acc[2];
#pragma unroll
    for (int nt = 0; nt < 2; ++nt) acc[nt] = zero4;

    const float* Xrow = X + (size_t)irow * INDIM;
    for (int kk = 0; kk < INDIM; kk += 32) {
        const int k0 = kk + q * 8;
        float4 xa = *(const float4*)(Xrow + k0);
        float4 xb = *(const float4*)(Xrow + k0 + 4);
        float xs[8] = {xa.x, xa.y, xa.z, xa.w, xb.x, xb.y, xb.z, xb.w};
        s16x8 ahi, alo;
#pragma unroll
        for (int j = 0; j < 8; ++j) { short h, l; split_bf(xs[j], h, l); ahi[j] = h; alo[j] = l; }
#pragma unroll
        for (int nt = 0; nt < 2; ++nt) {
            const int n = colbase + nt * 16 + m16;
            s16x8 bhi = *(const s16x8*)(W1Thi + n * INDIM + k0);
            s16x8 blo = *(const s16x8*)(W1Tlo + n * INDIM + k0);
            acc[nt] = __builtin_amdgcn_mfma_f32_16x16x32_bf16(ahi, bhi, acc[nt], 0, 0, 0);
            acc[nt] = __builtin_amdgcn_mfma_f32_16x16x32_bf16(ahi, blo, acc[nt], 0, 0, 0);
            acc[nt] = __builtin_amdgcn_mfma_f32_16x16x32_bf16(alo, bhi, acc[nt], 0, 0, 0);
        }
    }

    float p1[4] = {0.f, 0.f, 0.f, 0.f};
    float p2[4] = {0.f, 0.f, 0.f, 0.f};
    const int rowbase = i0 + q * 4;             // C rows: (lane>>4)*4 + r
    const int chunk = rowbase >> 5, win = rowbase & 31;
#pragma unroll
    for (int nt = 0; nt < 2; ++nt) {
        const int col = colbase + nt * 16 + m16;
        const float b1v = b1[col];
        const float a1v = avec[col];
        const float a2v = avec[HIDD + col];
        float v0 = acc[nt][0] + b1v;
        float v1 = acc[nt][1] + b1v;
        float v2 = acc[nt][2] + b1v;
        float v3 = acc[nt][3] + b1v;
        ushort4 us;
        us.x = (unsigned short)f2bf(v0);
        us.y = (unsigned short)f2bf(v1);
        us.z = (unsigned short)f2bf(v2);
        us.w = (unsigned short)f2bf(v3);
        *(ushort4*)(H1TB + (size_t)chunk * 8192 + col * 32 + win) = us;
        p1[0] += v0 * a1v; p1[1] += v1 * a1v; p1[2] += v2 * a1v; p1[3] += v3 * a1v;
        p2[0] += v0 * a2v; p2[1] += v1 * a2v; p2[2] += v2 * a2v; p2[3] += v3 * a2v;
    }
#pragma unroll
    for (int off = 1; off < 16; off <<= 1) {
#pragma unroll
        for (int r = 0; r < 4; ++r) {
            p1[r] += __shfl_xor(p1[r], off);
            p2[r] += __shfl_xor(p2[r], off);
        }
    }
    if (m16 == 0) {
#pragma unroll
        for (int r = 0; r < 4; ++r) {
            s1p[wn][q * 4 + r] = p1[r];
            s2p[wn][q * 4 + r] = p2[r];
        }
    }
    __syncthreads();
    if (tid < 16) {
        const int i = i0 + tid;
        float s1 = (s1p[0][tid] + s1p[1][tid]) + (s1p[2][tid] + s1p[3][tid]);
        float s2 = (s2p[0][tid] + s2p[1][tid]) + (s2p[2][tid] + s2p[3][tid]);
        atomicAdd(&s1w[i], s1);
        atomicAdd(&s2w[i], s2);
    }
}

// ---------------- kernel 1b: exp factors from s1/s2 totals -----------------------------
__global__ void __launch_bounds__(256)
k_uv(const float* __restrict__ s1w, const float* __restrict__ s2w,
     float* __restrict__ alw, float* __restrict__ bew, float* __restrict__ uvw) {
    const int i = blockIdx.x * 256 + threadIdx.x;
    const float s1 = s1w[i], s2 = s2w[i];
    alw[i] = expf(s1);
    bew[i] = expf(0.2f * s1);
    uvw[2 * i]     = expf(s2);
    uvw[2 * i + 1] = expf(0.2f * s2);
}

// ---------------- kernel 2: H2acc += W @ H1 (LDS dbuf + bitmask + XOR-swizzle) ---------
// Grid 1024, XCD-pinned decomposition: xcd = bid&7 (HW round-robin), ks = xcd>>1,
// mb = (bid>>3)*2 + (xcd&1)  [bijective: 128 bid>>3 values x 8 xcd = 1024].
// All blocks on one XCD share ONE 1MB H1TB slice -> L2-resident staging.
// Block 256 = 4 waves; 4 blk/CU. K-loop/epilogue identical to r8 (best).
__global__ void __launch_bounds__(256, 4)
k_attn(const unsigned int* __restrict__ Apk, const unsigned short* __restrict__ H1TB,
       const float* __restrict__ alw, const float* __restrict__ bew,
       const float* __restrict__ uvw,
       float* __restrict__ H2acc, float* __restrict__ Zw) {
    __shared__ unsigned short tile[2][8192];   // 32 KB: 2 x [256 hid][32 j], swizzled

    const int tid = threadIdx.x;
    const int wave = tid >> 6, lane = tid & 63;
    const int q = lane >> 4, m16 = lane & 15;
    const int wm = wave & 1, wn = wave >> 1;
    const int bid = blockIdx.x;
    const int xcd = bid & 7;
    const int ks = xcd >> 1;
    const int mb = ((bid >> 3) << 1) | (xcd & 1);
    const int i = mb * 32 + wm * 16 + m16;
    const float al = alw[i], be = bew[i];

    // staging source: pre-swizzled global offset (inverse of read-side XOR)
    const int tswz = tid ^ ((tid >> 3) & 3);
    const unsigned short* gp = H1TB + (size_t)ks * 64 * 8192 + tswz * 8;
    __attribute__((address_space(3))) unsigned short* tl =
        (__attribute__((address_space(3))) unsigned short*)&tile[0][0];

    const unsigned int* Ab = Apk + (size_t)i * 256 + ks * 64 + q * 16;
    const float* uvp = uvw + 2 * (ks * 2048 + q * 8);

    // read-side: h = wn*128 + nt*16 + m16; xor term is nt-independent
    const int hb0 = wn * 128 + m16;
    const int qx = (q * 8) ^ (((hb0 >> 1) & 3) << 3);   // swizzled j-offset

    f32x4 zero4 = {0.f, 0.f, 0.f, 0.f};
    f32x4 acc[8];
#pragma unroll
    for (int nt = 0; nt < 8; ++nt) acc[nt] = zero4;
    float zacc = 0.f;

    // ---- prologue: stage tile 0 into buf 0, then uv(0), then A dword 0 ----
#pragma unroll
    for (int c = 0; c < 4; ++c)
        __builtin_amdgcn_global_load_lds(
            (const __attribute__((address_space(1))) void*)(gp + c * 2048),
            (__attribute__((address_space(3))) void*)(tl + c * 2048 + tid * 8),
            16, 0, 0);
    gp += 8192;

    float4 uv0 = *(const float4*)(uvp);
    float4 uv1 = *(const float4*)(uvp + 4);
    float4 uv2 = *(const float4*)(uvp + 8);
    float4 uv3 = *(const float4*)(uvp + 12);
    uvp += 64;
    unsigned int a4 = Ab[0];

    for (int kk4 = 0; kk4 < 16; ++kk4) {
        // prefetch next A dword (covers ~1 K-step of latency before in-order retire)
        unsigned int a4n = Ab[(kk4 + 1) & 15];
#pragma unroll
        for (int kkq = 0; kkq < 4; ++kkq) {
            const int kk = kk4 * 4 + kkq;
            const unsigned int ab = a4 >> (kkq * 8);

            // ---- weight generation for this K-step ----
            float wv[8];
            wv[0] = (ab & 1u)   ? fmaxf(al * uv0.x, be * uv0.y) : 0.f;
            wv[1] = (ab & 2u)   ? fmaxf(al * uv0.z, be * uv0.w) : 0.f;
            wv[2] = (ab & 4u)   ? fmaxf(al * uv1.x, be * uv1.y) : 0.f;
            wv[3] = (ab & 8u)   ? fmaxf(al * uv1.z, be * uv1.w) : 0.f;
            wv[4] = (ab & 16u)  ? fmaxf(al * uv2.x, be * uv2.y) : 0.f;
            wv[5] = (ab & 32u)  ? fmaxf(al * uv2.z, be * uv2.w) : 0.f;
            wv[6] = (ab & 64u)  ? fmaxf(al * uv3.x, be * uv3.y) : 0.f;
            wv[7] = (ab & 128u) ? fmaxf(al * uv3.z, be * uv3.w) : 0.f;
            zacc += (wv[0] + wv[1] + wv[2] + wv[3]) + (wv[4] + wv[5] + wv[6] + wv[7]);
            s16x8 af;
#pragma unroll
            for (int j = 0; j < 8; ++j) af[j] = f2bf(wv[j]);

            // ---- barrier cluster: drain stage(kk) (issued one K-step ago) ----
            // At kkq==0 the a4n prefetch (issued above) is in flight: keep it.
            __builtin_amdgcn_sched_barrier(0);
            if (kkq == 0) asm volatile("s_waitcnt vmcnt(1)" ::: "memory");
            else          asm volatile("s_waitcnt vmcnt(0)" ::: "memory");
            __builtin_amdgcn_s_barrier();
            __builtin_amdgcn_sched_barrier(0);

            if (kk < 63) {
                // uv prefetch first, then issue stage(kk+1) into the other buffer
                uv0 = *(const float4*)(uvp);
                uv1 = *(const float4*)(uvp + 4);
                uv2 = *(const float4*)(uvp + 8);
                uv3 = *(const float4*)(uvp + 12);
                uvp += 64;
                const int nb = ((kk + 1) & 1) * 8192;
#pragma unroll
                for (int c = 0; c < 4; ++c)
                    __builtin_amdgcn_global_load_lds(
                        (const __attribute__((address_space(1))) void*)(gp + c * 2048),
                        (__attribute__((address_space(3))) void*)(tl + nb + c * 2048 + tid * 8),
                        16, 0, 0);
                gp += 8192;
            }

            // ---- MFMA phase on buf[kk&1] (swizzled reads) ----
            const unsigned short* tb = &tile[kk & 1][0];
#pragma unroll
            for (int nt = 0; nt < 8; ++nt) {
                s16x8 bfv = *(const s16x8*)(tb + (hb0 + nt * 16) * 32 + qx);
                acc[nt] = __builtin_amdgcn_mfma_f32_16x16x32_bf16(af, bfv, acc[nt], 0, 0, 0);
            }
        }
        a4 = a4n;
    }

    // Z row-sum: reduce across q groups; one atomic per row (wn==0 waves only).
    zacc += __shfl_xor(zacc, 16);
    zacc += __shfl_xor(zacc, 32);
    if (wn == 0 && q == 0) atomicAdd(&Zw[i], zacc);

    const int rowbase = mb * 32 + wm * 16 + q * 4;
#pragma unroll
    for (int nt = 0; nt < 8; ++nt) {
        const int col = wn * 128 + nt * 16 + m16;
#pragma unroll
        for (int r = 0; r < 4; ++r)
            atomicAdd(&H2acc[(size_t)(rowbase + r) * HIDD + col], acc[nt][r]);
    }
}

// ---------------- kernel 3: out = sigmoid((H2acc/Z) @ Omega + beta) --------------------
// Grid 512 (16 rows/block, 2 blocks/CU by 64KB LDS) for 2x TLP on the H2acc read.
__global__ void __launch_bounds__(256)
k_out(const float* __restrict__ H2acc, const float* __restrict__ Zw,
      const float* __restrict__ Omega, const float* __restrict__ beta,
      float* __restrict__ out) {
    __shared__ float om[HIDD * OUTD];  // 64 KB
    const int tid = threadIdx.x;
    for (int idx = tid; idx < HIDD * OUTD; idx += 256) om[idx] = Omega[idx];
    __syncthreads();
    const int wave = tid >> 6, o = tid & 63;
    const float bv = beta[o];
    for (int rr = 0; rr < 4; ++rr) {
        const int i = blockIdx.x * 16 + wave * 4 + rr;
        const float4* H2v = (const float4*)(H2acc + (size_t)i * HIDD);
        float acc = 0.f;
#pragma unroll 4
        for (int c4 = 0; c4 < 64; ++c4) {
            float4 h = H2v[c4];
            const int cb = c4 * 4;
            acc = fmaf(h.x, om[(cb + 0) * OUTD + o], acc);
            acc = fmaf(h.y, om[(cb + 1) * OUTD + o], acc);
            acc = fmaf(h.z, om[(cb + 2) * OUTD + o], acc);
            acc = fmaf(h.w, om[(cb + 3) * OUTD + o], acc);
        }
        const float zinv = 1.0f / Zw[i];
        const float logit = acc * zinv + bv;
        out[(size_t)i * OUTD + o] = 1.0f / (1.0f + expf(-logit));
    }
}

extern "C" void kernel_launch(void* const* d_in, const int* in_sizes, int n_in,
                              void* d_out, int out_size, void* d_ws, size_t ws_size,
                              hipStream_t stream) {
    const float* X     = (const float*)d_in[0];
    const int*   A     = (const int*)d_in[1];
    const float* W1    = (const float*)d_in[2];
    const float* b1    = (const float*)d_in[3];
    const float* avec  = (const float*)d_in[4];
    const float* Omega = (const float*)d_in[5];
    const float* beta  = (const float*)d_in[6];
    float* out = (float*)d_out;

    char* ws = (char*)d_ws;
    unsigned short* H1TB = (unsigned short*)(ws + 0);       // 4,194,304
    short* W1Thi = (short*)(ws + 4194304);                  // 262,144
    short* W1Tlo = (short*)(ws + 4456448);                  // 262,144
    float* s1w   = (float*)(ws + 4718592);                  // 32,768
    float* s2w   = (float*)(ws + 4751360);                  // 32,768
    float* alw   = (float*)(ws + 4784128);                  // 32,768
    float* bew   = (float*)(ws + 4816896);                  // 32,768
    float* uvw   = (float*)(ws + 4849664);                  // 65,536
    float* Zw    = (float*)(ws + 4915200);                  // 32,768
    float* H2acc = (float*)(ws + 4947968);                  // 8,388,608
    unsigned int* Apk = (unsigned int*)(ws + 13336576);     // 8,388,608 (end 21,725,184)

    // zero s1w..H2acc (8,617,984 B): covers s1w/s2w atomics, Zw, H2acc.
    hipMemsetAsync(s1w, 0, 8617984, stream);

    k_splitW1<<<512, 256, 0, stream>>>(W1, W1Thi, W1Tlo);
    k_h1<<<1024, 256, 0, stream>>>(X, W1Thi, W1Tlo, b1, avec, H1TB, s1w, s2w);
    k_uv<<<32, 256, 0, stream>>>(s1w, s2w, alw, bew, uvw);
    k_packA<<<8192, 256, 0, stream>>>(A, Apk);
    k_attn<<<1024, 256, 0, stream>>>(Apk, H1TB, alw, bew, uvw, H2acc, Zw);
    k_out<<<512, 256, 0, stream>>>(H2acc, Zw, Omega, beta, out);
}

// Round 12
// 533.341 us; speedup vs baseline: 1.1857x; 1.0056x over previous
//
#include <hip/hip_runtime.h>
#include <hip/hip_bf16.h>

// GAT forward: N=8192, IN=512, HID=256, OUT=64.
// w_ij = A_ij * max( e^{s1_i} e^{s2_j}, e^{0.2 s1_i} e^{0.2 s2_j} )
// Round 12: k_attn amortizes each staged 16KB tile over 64 rows (512-thr blocks,
// 8 waves = 4 row-groups x 2 hid-groups, grid 512): total staging traffic halves
// (1GB -> 512MB), barriers per output row halve. Occupancy unchanged (16 w/CU).
// Loop discipline/swizzle identical to r8/r11 (best, 535.9).

typedef float f32x4 __attribute__((ext_vector_type(4)));
typedef short s16x8 __attribute__((ext_vector_type(8)));

#define NN 8192
#define INDIM 512
#define HIDD 256
#define OUTD 64

static __device__ __forceinline__ short f2bf(float x) {
    __hip_bfloat16 h = __float2bfloat16(x);
    return __builtin_bit_cast(short, h);
}

static __device__ __forceinline__ void split_bf(float x, short& hi, short& lo) {
    short h = f2bf(x);
    unsigned int hb = ((unsigned int)(unsigned short)h) << 16;
    float hf = __builtin_bit_cast(float, hb);
    hi = h;
    lo = f2bf(x - hf);
}

// ---------------- kernel A: pack A (8192x8192 int32) -> bitmask ------------------------
// dword idx i*256 + ks*64 + q*16 + kk4, byte kkq, bit j <-> col = ks*2048+(kk4*4+kkq)*32+q*8+j
__global__ void __launch_bounds__(256)
k_packA(const int* __restrict__ A, unsigned int* __restrict__ Apk) {
    const int i = blockIdx.x;
    const int t = threadIdx.x;               // t = ks*64 + q*16 + kk0
    const int ks = t >> 6, q = (t >> 4) & 3, kk0 = t & 15;
    const int* Ar = A + (size_t)i * NN;
    unsigned int out = 0;
#pragma unroll
    for (int kkq = 0; kkq < 4; ++kkq) {
        const int kk = kk0 * 4 + kkq;
        const int c0 = ks * 2048 + kk * 32 + q * 8;
        int4 v0 = *(const int4*)(Ar + c0);
        int4 v1 = *(const int4*)(Ar + c0 + 4);
        unsigned int b = 0;
        b |= (v0.x > 0) ? 1u : 0u;
        b |= (v0.y > 0) ? 2u : 0u;
        b |= (v0.z > 0) ? 4u : 0u;
        b |= (v0.w > 0) ? 8u : 0u;
        b |= (v1.x > 0) ? 16u : 0u;
        b |= (v1.y > 0) ? 32u : 0u;
        b |= (v1.z > 0) ? 64u : 0u;
        b |= (v1.w > 0) ? 128u : 0u;
        out |= b << (kkq * 8);
    }
    Apk[(size_t)i * 256 + t] = out;
}

// ---------------- kernel 0: W1 (512x256 f32) -> W1^T hi/lo bf16 [256][512] -------------
__global__ void k_splitW1(const float* __restrict__ W1,
                          short* __restrict__ W1Thi, short* __restrict__ W1Tlo) {
    int t = blockIdx.x * 256 + threadIdx.x;   // t = n*512 + k
    int n = t >> 9;
    int k = t & 511;
    float x = W1[k * 256 + n];
    short hi, lo; split_bf(x, hi, lo);
    W1Thi[t] = hi;
    W1Tlo[t] = lo;
}

// ---------------- kernel 1: H1 = X@W1+b1 (split-bf16 MFMA, column-split) ---------------
// Grid 1024 = 512 row-tiles x 2 col-halves -> 4 blocks/CU (4 waves/SIMD TLP).
__global__ void __launch_bounds__(256, 4)
k_h1(const float* __restrict__ X, const short* __restrict__ W1Thi,
     const short* __restrict__ W1Tlo, const float* __restrict__ b1,
     const float* __restrict__ avec, unsigned short* __restrict__ H1TB,
     float* __restrict__ s1w, float* __restrict__ s2w) {
    __shared__ float s1p[4][16];
    __shared__ float s2p[4][16];
    const int tid = threadIdx.x;
    const int wn = tid >> 6, lane = tid & 63;
    const int q = lane >> 4, m16 = lane & 15;
    const int rt = blockIdx.x >> 1;
    const int ch = blockIdx.x & 1;
    const int i0 = rt * 16;
    const int irow = i0 + m16;
    const int colbase = ch * 128 + wn * 32;

    f32x4 zero4 = {0.f, 0.f, 0.f, 0.f};
    f32x4 acc[2];
#pragma unroll
    for (int nt = 0; nt < 2; ++nt) acc[nt] = zero4;

    const float* Xrow = X + (size_t)irow * INDIM;
    for (int kk = 0; kk < INDIM; kk += 32) {
        const int k0 = kk + q * 8;
        float4 xa = *(const float4*)(Xrow + k0);
        float4 xb = *(const float4*)(Xrow + k0 + 4);
        float xs[8] = {xa.x, xa.y, xa.z, xa.w, xb.x, xb.y, xb.z, xb.w};
        s16x8 ahi, alo;
#pragma unroll
        for (int j = 0; j < 8; ++j) { short h, l; split_bf(xs[j], h, l); ahi[j] = h; alo[j] = l; }
#pragma unroll
        for (int nt = 0; nt < 2; ++nt) {
            const int n = colbase + nt * 16 + m16;
            s16x8 bhi = *(const s16x8*)(W1Thi + n * INDIM + k0);
            s16x8 blo = *(const s16x8*)(W1Tlo + n * INDIM + k0);
            acc[nt] = __builtin_amdgcn_mfma_f32_16x16x32_bf16(ahi, bhi, acc[nt], 0, 0, 0);
            acc[nt] = __builtin_amdgcn_mfma_f32_16x16x32_bf16(ahi, blo, acc[nt], 0, 0, 0);
            acc[nt] = __builtin_amdgcn_mfma_f32_16x16x32_bf16(alo, bhi, acc[nt], 0, 0, 0);
        }
    }

    float p1[4] = {0.f, 0.f, 0.f, 0.f};
    float p2[4] = {0.f, 0.f, 0.f, 0.f};
    const int rowbase = i0 + q * 4;             // C rows: (lane>>4)*4 + r
    const int chunk = rowbase >> 5, win = rowbase & 31;
#pragma unroll
    for (int nt = 0; nt < 2; ++nt) {
        const int col = colbase + nt * 16 + m16;
        const float b1v = b1[col];
        const float a1v = avec[col];
        const float a2v = avec[HIDD + col];
        float v0 = acc[nt][0] + b1v;
        float v1 = acc[nt][1] + b1v;
        float v2 = acc[nt][2] + b1v;
        float v3 = acc[nt][3] + b1v;
        ushort4 us;
        us.x = (unsigned short)f2bf(v0);
        us.y = (unsigned short)f2bf(v1);
        us.z = (unsigned short)f2bf(v2);
        us.w = (unsigned short)f2bf(v3);
        *(ushort4*)(H1TB + (size_t)chunk * 8192 + col * 32 + win) = us;
        p1[0] += v0 * a1v; p1[1] += v1 * a1v; p1[2] += v2 * a1v; p1[3] += v3 * a1v;
        p2[0] += v0 * a2v; p2[1] += v1 * a2v; p2[2] += v2 * a2v; p2[3] += v3 * a2v;
    }
#pragma unroll
    for (int off = 1; off < 16; off <<= 1) {
#pragma unroll
        for (int r = 0; r < 4; ++r) {
            p1[r] += __shfl_xor(p1[r], off);
            p2[r] += __shfl_xor(p2[r], off);
        }
    }
    if (m16 == 0) {
#pragma unroll
        for (int r = 0; r < 4; ++r) {
            s1p[wn][q * 4 + r] = p1[r];
            s2p[wn][q * 4 + r] = p2[r];
        }
    }
    __syncthreads();
    if (tid < 16) {
        const int i = i0 + tid;
        float s1 = (s1p[0][tid] + s1p[1][tid]) + (s1p[2][tid] + s1p[3][tid]);
        float s2 = (s2p[0][tid] + s2p[1][tid]) + (s2p[2][tid] + s2p[3][tid]);
        atomicAdd(&s1w[i], s1);
        atomicAdd(&s2w[i], s2);
    }
}

// ---------------- kernel 1b: exp factors from s1/s2 totals -----------------------------
__global__ void __launch_bounds__(256)
k_uv(const float* __restrict__ s1w, const float* __restrict__ s2w,
     float* __restrict__ alw, float* __restrict__ bew, float* __restrict__ uvw) {
    const int i = blockIdx.x * 256 + threadIdx.x;
    const float s1 = s1w[i], s2 = s2w[i];
    alw[i] = expf(s1);
    bew[i] = expf(0.2f * s1);
    uvw[2 * i]     = expf(s2);
    uvw[2 * i + 1] = expf(0.2f * s2);
}

// ---------------- kernel 2: H2acc += W @ H1 (LDS dbuf + bitmask + XOR-swizzle) ---------
// Grid 512, block 512 = 8 waves: wm = wave>>1 (4 row-groups of 16), wn = wave&1
// (128-hid half). 64 rows share each staged 16KB tile -> staging traffic halved
// vs r8. XCD-pinned: xcd = bid&7, ks = xcd>>1, mb = (bid>>3)*2 + (xcd&1) (0..127).
// 2 blocks/CU (32KB LDS) = 16 waves/CU, same occupancy as r8. Per-thread staging
// = 2 ops/iter; barrier waits vmcnt(1) at kkq==0 (A-prefetch in flight) else 0.
__global__ void __launch_bounds__(512, 4)
k_attn(const unsigned int* __restrict__ Apk, const unsigned short* __restrict__ H1TB,
       const float* __restrict__ alw, const float* __restrict__ bew,
       const float* __restrict__ uvw,
       float* __restrict__ H2acc, float* __restrict__ Zw) {
    __shared__ unsigned short tile[2][8192];   // 32 KB: 2 x [256 hid][32 j], swizzled

    const int tid = threadIdx.x;
    const int wave = tid >> 6, lane = tid & 63;
    const int q = lane >> 4, m16 = lane & 15;
    const int wm = wave >> 1, wn = wave & 1;
    const int bid = blockIdx.x;
    const int xcd = bid & 7;
    const int ks = xcd >> 1;
    const int mb = ((bid >> 3) << 1) | (xcd & 1);          // 0..127, 64 rows each
    const int i = mb * 64 + wm * 16 + m16;
    const float al = alw[i], be = bew[i];

    // staging source: pre-swizzled global offset (inverse of read-side XOR).
    // Swizzle XORs ushort-idx bits [3:4] with [6:7] = tid bits [0:1] with [3:4];
    // c-offsets (4096 ushorts) are above bit 11 -> formula valid for tid<512.
    const int tswz = tid ^ ((tid >> 3) & 3);
    const unsigned short* gp = H1TB + (size_t)ks * 64 * 8192 + tswz * 8;
    __attribute__((address_space(3))) unsigned short* tl =
        (__attribute__((address_space(3))) unsigned short*)&tile[0][0];

    const unsigned int* Ab = Apk + (size_t)i * 256 + ks * 64 + q * 16;
    const float* uvp = uvw + 2 * (ks * 2048 + q * 8);

    // read-side: h = wn*128 + nt*16 + m16; xor term is nt-independent
    const int hb0 = wn * 128 + m16;
    const int qx = (q * 8) ^ (((hb0 >> 1) & 3) << 3);   // swizzled j-offset

    f32x4 zero4 = {0.f, 0.f, 0.f, 0.f};
    f32x4 acc[8];
#pragma unroll
    for (int nt = 0; nt < 8; ++nt) acc[nt] = zero4;
    float zacc = 0.f;

    // ---- prologue: stage tile 0 into buf 0, then uv(0), then A dword 0 ----
#pragma unroll
    for (int c = 0; c < 2; ++c)
        __builtin_amdgcn_global_load_lds(
            (const __attribute__((address_space(1))) void*)(gp + c * 4096),
            (__attribute__((address_space(3))) void*)(tl + c * 4096 + tid * 8),
            16, 0, 0);
    gp += 8192;

    float4 uv0 = *(const float4*)(uvp);
    float4 uv1 = *(const float4*)(uvp + 4);
    float4 uv2 = *(const float4*)(uvp + 8);
    float4 uv3 = *(const float4*)(uvp + 12);
    uvp += 64;
    unsigned int a4 = Ab[0];

    for (int kk4 = 0; kk4 < 16; ++kk4) {
        // prefetch next A dword (covers ~1 K-step of latency before in-order retire)
        unsigned int a4n = Ab[(kk4 + 1) & 15];
#pragma unroll
        for (int kkq = 0; kkq < 4; ++kkq) {
            const int kk = kk4 * 4 + kkq;
            const unsigned int ab = a4 >> (kkq * 8);

            // ---- weight generation for this K-step ----
            float wv[8];
            wv[0] = (ab & 1u)   ? fmaxf(al * uv0.x, be * uv0.y) : 0.f;
            wv[1] = (ab & 2u)   ? fmaxf(al * uv0.z, be * uv0.w) : 0.f;
            wv[2] = (ab & 4u)   ? fmaxf(al * uv1.x, be * uv1.y) : 0.f;
            wv[3] = (ab & 8u)   ? fmaxf(al * uv1.z, be * uv1.w) : 0.f;
            wv[4] = (ab & 16u)  ? fmaxf(al * uv2.x, be * uv2.y) : 0.f;
            wv[5] = (ab & 32u)  ? fmaxf(al * uv2.z, be * uv2.w) : 0.f;
            wv[6] = (ab & 64u)  ? fmaxf(al * uv3.x, be * uv3.y) : 0.f;
            wv[7] = (ab & 128u) ? fmaxf(al * uv3.z, be * uv3.w) : 0.f;
            zacc += (wv[0] + wv[1] + wv[2] + wv[3]) + (wv[4] + wv[5] + wv[6] + wv[7]);
            s16x8 af;
#pragma unroll
            for (int j = 0; j < 8; ++j) af[j] = f2bf(wv[j]);

            // ---- barrier cluster: drain stage(kk) (issued one K-step ago) ----
            // At kkq==0 the a4n prefetch (issued above) is in flight: keep it.
            __builtin_amdgcn_sched_barrier(0);
            if (kkq == 0) asm volatile("s_waitcnt vmcnt(1)" ::: "memory");
            else          asm volatile("s_waitcnt vmcnt(0)" ::: "memory");
            __builtin_amdgcn_s_barrier();
            __builtin_amdgcn_sched_barrier(0);

            if (kk < 63) {
                // uv prefetch first, then issue stage(kk+1) into the other buffer
                uv0 = *(const float4*)(uvp);
                uv1 = *(const float4*)(uvp + 4);
                uv2 = *(const float4*)(uvp + 8);
                uv3 = *(const float4*)(uvp + 12);
                uvp += 64;
                const int nb = ((kk + 1) & 1) * 8192;
#pragma unroll
                for (int c = 0; c < 2; ++c)
                    __builtin_amdgcn_global_load_lds(
                        (const __attribute__((address_space(1))) void*)(gp + c * 4096),
                        (__attribute__((address_space(3))) void*)(tl + nb + c * 4096 + tid * 8),
                        16, 0, 0);
                gp += 8192;
            }

            // ---- MFMA phase on buf[kk&1] (swizzled reads) ----
            const unsigned short* tb = &tile[kk & 1][0];
#pragma unroll
            for (int nt = 0; nt < 8; ++nt) {
                s16x8 bfv = *(const s16x8*)(tb + (hb0 + nt * 16) * 32 + qx);
                acc[nt] = __builtin_amdgcn_mfma_f32_16x16x32_bf16(af, bfv, acc[nt], 0, 0, 0);
            }
        }
        a4 = a4n;
    }

    // Z row-sum: reduce across q groups; wn==0 waves (wm 0..3) cover all 64 rows.
    zacc += __shfl_xor(zacc, 16);
    zacc += __shfl_xor(zacc, 32);
    if (wn == 0 && q == 0) atomicAdd(&Zw[i], zacc);

    const int rowbase = mb * 64 + wm * 16 + q * 4;
#pragma unroll
    for (int nt = 0; nt < 8; ++nt) {
        const int col = wn * 128 + nt * 16 + m16;
#pragma unroll
        for (int r = 0; r < 4; ++r)
            atomicAdd(&H2acc[(size_t)(rowbase + r) * HIDD + col], acc[nt][r]);
    }
}

// ---------------- kernel 3: out = sigmoid((H2acc/Z) @ Omega + beta) --------------------
// Grid 512 (16 rows/block, 2 blocks/CU by 64KB LDS) for 2x TLP on the H2acc read.
__global__ void __launch_bounds__(256)
k_out(const float* __restrict__ H2acc, const float* __restrict__ Zw,
      const float* __restrict__ Omega, const float* __restrict__ beta,
      float* __restrict__ out) {
    __shared__ float om[HIDD * OUTD];  // 64 KB
    const int tid = threadIdx.x;
    for (int idx = tid; idx < HIDD * OUTD; idx += 256) om[idx] = Omega[idx];
    __syncthreads();
    const int wave = tid >> 6, o = tid & 63;
    const float bv = beta[o];
    for (int rr = 0; rr < 4; ++rr) {
        const int i = blockIdx.x * 16 + wave * 4 + rr;
        const float4* H2v = (const float4*)(H2acc + (size_t)i * HIDD);
        float acc = 0.f;
#pragma unroll 4
        for (int c4 = 0; c4 < 64; ++c4) {
            float4 h = H2v[c4];
            const int cb = c4 * 4;
            acc = fmaf(h.x, om[(cb + 0) * OUTD + o], acc);
            acc = fmaf(h.y, om[(cb + 1) * OUTD + o], acc);
            acc = fmaf(h.z, om[(cb + 2) * OUTD + o], acc);
            acc = fmaf(h.w, om[(cb + 3) * OUTD + o], acc);
        }
        const float zinv = 1.0f / Zw[i];
        const float logit = acc * zinv + bv;
        out[(size_t)i * OUTD + o] = 1.0f / (1.0f + expf(-logit));
    }
}

extern "C" void kernel_launch(void* const* d_in, const int* in_sizes, int n_in,
                              void* d_out, int out_size, void* d_ws, size_t ws_size,
                              hipStream_t stream) {
    const float* X     = (const float*)d_in[0];
    const int*   A     = (const int*)d_in[1];
    const float* W1    = (const float*)d_in[2];
    const float* b1    = (const float*)d_in[3];
    const float* avec  = (const float*)d_in[4];
    const float* Omega = (const float*)d_in[5];
    const float* beta  = (const float*)d_in[6];
    float* out = (float*)d_out;

    char* ws = (char*)d_ws;
    unsigned short* H1TB = (unsigned short*)(ws + 0);       // 4,194,304
    short* W1Thi = (short*)(ws + 4194304);                  // 262,144
    short* W1Tlo = (short*)(ws + 4456448);                  // 262,144
    float* s1w   = (float*)(ws + 4718592);                  // 32,768
    float* s2w   = (float*)(ws + 4751360);                  // 32,768
    float* alw   = (float*)(ws + 4784128);                  // 32,768
    float* bew   = (float*)(ws + 4816896);                  // 32,768
    float* uvw   = (float*)(ws + 4849664);                  // 65,536
    float* Zw    = (float*)(ws + 4915200);                  // 32,768
    float* H2acc = (float*)(ws + 4947968);                  // 8,388,608
    unsigned int* Apk = (unsigned int*)(ws + 13336576);     // 8,388,608 (end 21,725,184)

    // zero s1w..H2acc (8,617,984 B): covers s1w/s2w atomics, Zw, H2acc.
    hipMemsetAsync(s1w, 0, 8617984, stream);

    k_splitW1<<<512, 256, 0, stream>>>(W1, W1Thi, W1Tlo);
    k_h1<<<1024, 256, 0, stream>>>(X, W1Thi, W1Tlo, b1, avec, H1TB, s1w, s2w);
    k_uv<<<32, 256, 0, stream>>>(s1w, s2w, alw, bew, uvw);
    k_packA<<<8192, 256, 0, stream>>>(A, Apk);
    k_attn<<<512, 512, 0, stream>>>(Apk, H1TB, alw, bew, uvw, H2acc, Zw);
    k_out<<<512, 256, 0, stream>>>(H2acc, Zw, Omega, beta, out);
}